// Round 1
// baseline (208.796 us; speedup 1.0000x reference)
//
#include <hip/hip_runtime.h>

// Problem constants (from reference): WINDOW_SIZE=2, resolution/min-range for
// cartesian->radar conversion.
#define RES  0.2592
#define MINR 82.8144   // (640/2 - 0.5) * 0.2592

// ---------------------------------------------------------------------------
// Kernel 1: per-batch weighted reduction of 9 RAW-PIXEL moments over N points.
//   acc = [ W, Px, Py, Qx, Qy, Rxx, Rxy, Ryx, Ryy ]
// where P = sum w*src_raw, Q = sum w*tgt_raw, R_ab = sum w * t_a * s_b
// (raw pixel coords). The affine radar-frame conversion is EXACT on moments,
// so it is applied once per batch in the finalize kernel instead of per point
// (saves 4 f64 FMA/point). f64 accumulation for the N=100k cancellation.
//
// No atomics / no pre-zeroed workspace: each block writes its 9 partials to
// ws[(batch*bpb + blockIdx.x)*9 + k]; finalize sums the bpb slots.
// Grid: (bpb, B). Quad-granularity: 4 points (2 pairs) per lane-iteration.
// ---------------------------------------------------------------------------
__global__ __launch_bounds__(256) void svd_reduce(
    const float4* __restrict__ kp,   // keypoint_coords viewed as pairs-of-points
    const float4* __restrict__ tg,   // tgt_coords viewed as pairs-of-points
    const float4* __restrict__ wq4,  // weights viewed as quads (4 weights)
    const float2* __restrict__ wt2,  // weights viewed as pairs (odd-tail only)
    double* __restrict__ ws,         // [B][bpb][9] per-block partials
    int npairs, int bpb)
{
    const int batch  = blockIdx.y;
    const int nquads = npairs >> 1;
    // src takes every WINDOW_SIZE=2-th row of keypoint_coords -> row 2*batch
    const float4* __restrict__ src = kp  + (size_t)(2 * batch) * npairs;
    const float4* __restrict__ tgt = tg  + (size_t)batch * npairs;
    const float4* __restrict__ wq  = wq4 + (size_t)batch * nquads;

    double aW = 0, aPx = 0, aPy = 0, aQx = 0, aQy = 0;
    double aXX = 0, aXY = 0, aYX = 0, aYY = 0;

    #define POINT(wf, sxf, syf, txf, tyf) do {                 \
        double w  = (double)(wf);                              \
        double sx = (double)(sxf), sy = (double)(syf);         \
        double tx = (double)(txf), ty = (double)(tyf);         \
        double wtx = w * tx, wty = w * ty;                     \
        aW  += w;                                              \
        aPx += w * sx;   aPy += w * sy;                        \
        aQx += wtx;      aQy += wty;                           \
        aXX += wtx * sx; aXY += wtx * sy;                      \
        aYX += wty * sx; aYY += wty * sy;                      \
    } while (0)

    for (int i = blockIdx.x * 256 + threadIdx.x; i < nquads; i += bpb * 256) {
        float4 s0 = src[2 * i], s1 = src[2 * i + 1];
        float4 t0 = tgt[2 * i], t1 = tgt[2 * i + 1];
        float4 w4 = wq[i];
        POINT(w4.x, s0.x, s0.y, t0.x, t0.y);
        POINT(w4.y, s0.z, s0.w, t0.z, t0.w);
        POINT(w4.z, s1.x, s1.y, t1.x, t1.y);
        POINT(w4.w, s1.z, s1.w, t1.z, t1.w);
    }
    // leftover pair when npairs is odd (not hit for this dataset: npairs=50000)
    if ((npairs & 1) && blockIdx.x == 0 && threadIdx.x == 0) {
        int i = npairs - 1;
        float4 s4 = src[i], t4 = tgt[i];
        float2 w2 = wt2[(size_t)batch * npairs + i];
        POINT(w2.x, s4.x, s4.y, t4.x, t4.y);
        POINT(w2.y, s4.z, s4.w, t4.z, t4.w);
    }
    #undef POINT

    double acc[9] = {aW, aPx, aPy, aQx, aQy, aXX, aXY, aYX, aYY};

    // 64-lane wave reduction (wavefront = 64 on CDNA)
    #pragma unroll
    for (int k = 0; k < 9; k++) {
        #pragma unroll
        for (int off = 32; off > 0; off >>= 1)
            acc[k] += __shfl_down(acc[k], off, 64);
    }

    __shared__ double sred[4][9];
    const int lane = threadIdx.x & 63;
    const int wid  = threadIdx.x >> 6;
    if (lane == 0) {
        #pragma unroll
        for (int k = 0; k < 9; k++) sred[wid][k] = acc[k];
    }
    __syncthreads();
    if (threadIdx.x < 9) {
        double v = sred[0][threadIdx.x] + sred[1][threadIdx.x] +
                   sred[2][threadIdx.x] + sred[3][threadIdx.x];
        ws[((size_t)batch * bpb + blockIdx.x) * 9 + threadIdx.x] = v;
    }
}

// ---------------------------------------------------------------------------
// Kernel 2: sum per-block partials, apply the affine conversion to the raw
// moments, then closed-form polar factor. One thread per batch.
//
// Affine: s' = (MINR - RES*sy_raw, RES*sx_raw - MINR), same for t'.
//   Sx' = MINR*W - RES*Py          Tx' = MINR*W - RES*Qy
//   Sy' = RES*Px - MINR*W          Ty' = RES*Qx - MINR*W
//   M'xx = M^2 W - MR(Py+Qy) + R^2 Ryy     M'xy = MR Px - M^2 W + MR Qy - R^2 Ryx
//   M'yx = MR Qx + MR Py - M^2 W - R^2 Rxy M'yy = R^2 Rxx - MR(Px+Qx) + M^2 W
//
// Wc's 3rd row/col are exactly zero, so the 3x3 SVD collapses:
//   R2 = polar factor U2*V2h of the 2x2 covariance A; R[2][2] = sign(det A).
// ---------------------------------------------------------------------------
__global__ void svd_finalize(const double* __restrict__ ws,
                             float* __restrict__ out, int B, int bpb)
{
    int b = blockIdx.x * blockDim.x + threadIdx.x;
    if (b >= B) return;

    double m[9] = {0, 0, 0, 0, 0, 0, 0, 0, 0};
    const double* p = ws + (size_t)b * bpb * 9;
    for (int j = 0; j < bpb; ++j) {
        #pragma unroll
        for (int k = 0; k < 9; ++k) m[k] += p[j * 9 + k];
    }

    double W  = m[0];
    double Px = m[1], Py = m[2], Qx = m[3], Qy = m[4];
    double Rxx = m[5], Rxy = m[6], Ryx = m[7], Ryy = m[8];

    // affine-correct the raw moments into the radar frame
    const double MR = MINR * RES, RR = RES * RES;
    double MW = MINR * W;
    double Sx = MW - RES * Py;
    double Sy = RES * Px - MW;
    double Tx = MW - RES * Qy;
    double Ty = RES * Qx - MW;
    double Mxx = MINR * MW - MR * (Py + Qy) + RR * Ryy;
    double Mxy = MR * Px - MINR * MW + MR * Qy - RR * Ryx;
    double Myx = MR * Qx + MR * Py - MINR * MW - RR * Rxy;
    double Myy = RR * Rxx - MR * (Px + Qx) + MINR * MW;

    double invW = 1.0 / W;
    // A[i][j] = (M_ij - T_i * S_j / W) / W   (i: tgt row, j: src col)
    double a  = (Mxx - Tx * Sx * invW) * invW;
    double bb = (Mxy - Tx * Sy * invW) * invW;
    double c  = (Myx - Ty * Sx * invW) * invW;
    double d  = (Myy - Ty * Sy * invW) * invW;

    double h1 = sqrt((a + d) * (a + d) + (bb - c) * (bb - c));
    double h2 = sqrt((a - d) * (a - d) + (bb + c) * (bb + c));

    double q00, q01, q10, q11, sgn;
    if (h1 >= h2) {            // det A >= 0 : rotation
        double inv = 1.0 / h1;
        q00 = (a + d) * inv;  q01 = (bb - c) * inv;
        q10 = (c - bb) * inv; q11 = (a + d) * inv;
        sgn = 1.0;
    } else {                   // det A < 0 : reflection (still exactly U2*V2h)
        double inv = 1.0 / h2;
        q00 = (a - d) * inv;  q01 = (bb + c) * inv;
        q10 = (bb + c) * inv; q11 = (d - a) * inv;
        sgn = -1.0;
    }

    double sx = Sx * invW, sy = Sy * invW;
    double tx = Tx * invW, ty = Ty * invW;

    // t1 = src_centroid - R^T * tgt_centroid
    double t1x = sx - (q00 * tx + q10 * ty);
    double t1y = sy - (q01 * tx + q11 * ty);
    // t_out = -R * t1
    double ox = -(q00 * t1x + q01 * t1y);
    double oy = -(q10 * t1x + q11 * t1y);

    // Output 0: R_tgt_src.transpose(0,2,1), row-major per batch.
    float* R = out + (size_t)b * 9;
    R[0] = (float)q00; R[1] = (float)q10; R[2] = 0.0f;
    R[3] = (float)q01; R[4] = (float)q11; R[5] = 0.0f;
    R[6] = 0.0f;       R[7] = 0.0f;       R[8] = (float)sgn;

    // Output 1: t_src_tgt_intgt, (B,3,1) appended after the B*9 rotations.
    float* T = out + (size_t)B * 9 + (size_t)b * 3;
    T[0] = (float)ox; T[1] = (float)oy; T[2] = 0.0f;
}

extern "C" void kernel_launch(void* const* d_in, const int* in_sizes, int n_in,
                              void* d_out, int out_size, void* d_ws, size_t ws_size,
                              hipStream_t stream) {
    const float* kp = (const float*)d_in[0];  // (B*2, N, 2) f32
    const float* tg = (const float*)d_in[1];  // (B,   N, 2) f32
    const float* wt = (const float*)d_in[2];  // (B, 1, N)   f32
    float* out = (float*)d_out;               // B*9 + B*3 f32

    const int B = out_size / 12;              // 64
    const int N = in_sizes[2] / B;            // 100000
    const int npairs = N / 2;                 // N is even
    const int BPB = 32;                       // blocks per batch -> 2048 blocks

    // No memset: svd_reduce writes every partial slot it owns, svd_finalize
    // reads exactly those slots. (d_ws poison is irrelevant.)
    dim3 grid(BPB, B);
    svd_reduce<<<grid, 256, 0, stream>>>(
        (const float4*)kp, (const float4*)tg,
        (const float4*)wt, (const float2*)wt,
        (double*)d_ws, npairs, BPB);

    svd_finalize<<<(B + 63) / 64, 64, 0, stream>>>((const double*)d_ws, out, B, BPB);
}

// Round 2
// 196.543 us; speedup vs baseline: 1.0623x; 1.0623x over previous
//
#include <hip/hip_runtime.h>

// Problem constants (from reference): WINDOW_SIZE=2, resolution/min-range for
// cartesian->radar conversion.
#define RES  0.2592
#define MINR 82.8144   // (640/2 - 0.5) * 0.2592

// ---------------------------------------------------------------------------
// Kernel 1: per-batch weighted reduction of 9 RAW-PIXEL moments over N points.
//   acc = [ W, Px, Py, Qx, Qy, Rxx, Rxy, Ryx, Ryy ]
// where P = sum w*src_raw, Q = sum w*tgt_raw, R_ab = sum w * t_a * s_b
// (raw pixel coords). The affine radar-frame conversion is EXACT on moments,
// so it is applied once per batch in finalize instead of per point.
// f64 accumulation (centroid-subtraction cancellation at N=100k needs it).
//
// Access pattern: pair-granularity, fully contiguous float4/float2 loads
// (16B/lane, 100% cacheline utilization per instruction). Round-1's quad
// variant (stride-32B per lane) regressed — reverted.
//
// No atomics / no pre-zeroed workspace: block writes its 9 partials to the
// TRANSPOSED layout ws[(batch*9 + k)*bpb + blockIdx.x] so finalize's lanes
// read each moment coalesced.
// ---------------------------------------------------------------------------
__global__ __launch_bounds__(256) void svd_reduce(
    const float4* __restrict__ kp,   // keypoint_coords viewed as pairs-of-points
    const float4* __restrict__ tg,   // tgt_coords viewed as pairs-of-points
    const float2* __restrict__ wt,   // weights viewed as pairs
    double* __restrict__ ws,         // [B][9][bpb] per-block partials
    int npairs, int bpb)
{
    const int batch = blockIdx.y;
    // src takes every WINDOW_SIZE=2-th row of keypoint_coords -> row 2*batch
    const float4* __restrict__ src = kp + (size_t)(2 * batch) * npairs;
    const float4* __restrict__ tgt = tg + (size_t)batch * npairs;
    const float2* __restrict__ wp  = wt + (size_t)batch * npairs;

    double aW = 0, aPx = 0, aPy = 0, aQx = 0, aQy = 0;
    double aXX = 0, aXY = 0, aYX = 0, aYY = 0;

    #define POINT(wf, sxf, syf, txf, tyf) do {                 \
        double w  = (double)(wf);                              \
        double sx = (double)(sxf), sy = (double)(syf);         \
        double tx = (double)(txf), ty = (double)(tyf);         \
        double wtx = w * tx, wty = w * ty;                     \
        aW  += w;                                              \
        aPx += w * sx;   aPy += w * sy;                        \
        aQx += wtx;      aQy += wty;                           \
        aXX += wtx * sx; aXY += wtx * sy;                      \
        aYX += wty * sx; aYY += wty * sy;                      \
    } while (0)

    for (int i = blockIdx.x * 256 + threadIdx.x; i < npairs; i += bpb * 256) {
        float4 s4 = src[i];
        float4 t4 = tgt[i];
        float2 w2 = wp[i];
        POINT(w2.x, s4.x, s4.y, t4.x, t4.y);
        POINT(w2.y, s4.z, s4.w, t4.z, t4.w);
    }
    #undef POINT

    double acc[9] = {aW, aPx, aPy, aQx, aQy, aXX, aXY, aYX, aYY};

    // 64-lane wave reduction (wavefront = 64 on CDNA)
    #pragma unroll
    for (int k = 0; k < 9; k++) {
        #pragma unroll
        for (int off = 32; off > 0; off >>= 1)
            acc[k] += __shfl_down(acc[k], off, 64);
    }

    __shared__ double sred[4][9];
    const int lane = threadIdx.x & 63;
    const int wid  = threadIdx.x >> 6;
    if (lane == 0) {
        #pragma unroll
        for (int k = 0; k < 9; k++) sred[wid][k] = acc[k];
    }
    __syncthreads();
    if (threadIdx.x < 9) {
        double v = sred[0][threadIdx.x] + sred[1][threadIdx.x] +
                   sred[2][threadIdx.x] + sred[3][threadIdx.x];
        // transposed partial layout: [batch][moment k][block]
        ws[((size_t)batch * 9 + threadIdx.x) * bpb + blockIdx.x] = v;
    }
}

// ---------------------------------------------------------------------------
// Kernel 2: one 64-thread block per batch. Lanes 0..bpb-1 each hold one
// block-partial per moment; wave shuffle-reduce (all loads in flight at once,
// 64 blocks concurrent -> no serial latency chain). Lane 0 applies the
// affine conversion to the raw moments + closed-form polar factor.
//
// Affine: s' = (MINR - RES*sy_raw, RES*sx_raw - MINR), same for t'.
// Wc's 3rd row/col are exactly zero, so the 3x3 SVD collapses:
//   R2 = polar factor U2*V2h of the 2x2 covariance A; R[2][2] = sign(det A).
// ---------------------------------------------------------------------------
__global__ __launch_bounds__(64) void svd_finalize(
    const double* __restrict__ ws, float* __restrict__ out, int B, int bpb)
{
    const int b    = blockIdx.x;
    const int lane = threadIdx.x;   // 0..63

    double m[9];
    #pragma unroll
    for (int k = 0; k < 9; k++) {
        // coalesced: lanes 0..bpb-1 read consecutive doubles
        double v = (lane < bpb) ? ws[((size_t)b * 9 + k) * bpb + lane] : 0.0;
        #pragma unroll
        for (int off = 32; off > 0; off >>= 1)
            v += __shfl_down(v, off, 64);
        m[k] = v;
    }
    if (lane != 0) return;

    double W  = m[0];
    double Px = m[1], Py = m[2], Qx = m[3], Qy = m[4];
    double Rxx = m[5], Rxy = m[6], Ryx = m[7], Ryy = m[8];

    // affine-correct the raw moments into the radar frame
    const double MR = MINR * RES, RR = RES * RES;
    double MW = MINR * W;
    double Sx = MW - RES * Py;
    double Sy = RES * Px - MW;
    double Tx = MW - RES * Qy;
    double Ty = RES * Qx - MW;
    double Mxx = MINR * MW - MR * (Py + Qy) + RR * Ryy;
    double Mxy = MR * Px - MINR * MW + MR * Qy - RR * Ryx;
    double Myx = MR * Qx + MR * Py - MINR * MW - RR * Rxy;
    double Myy = RR * Rxx - MR * (Px + Qx) + MINR * MW;

    double invW = 1.0 / W;
    // A[i][j] = (M_ij - T_i * S_j / W) / W   (i: tgt row, j: src col)
    double a  = (Mxx - Tx * Sx * invW) * invW;
    double bb = (Mxy - Tx * Sy * invW) * invW;
    double c  = (Myx - Ty * Sx * invW) * invW;
    double d  = (Myy - Ty * Sy * invW) * invW;

    double h1 = sqrt((a + d) * (a + d) + (bb - c) * (bb - c));
    double h2 = sqrt((a - d) * (a - d) + (bb + c) * (bb + c));

    double q00, q01, q10, q11, sgn;
    if (h1 >= h2) {            // det A >= 0 : rotation
        double inv = 1.0 / h1;
        q00 = (a + d) * inv;  q01 = (bb - c) * inv;
        q10 = (c - bb) * inv; q11 = (a + d) * inv;
        sgn = 1.0;
    } else {                   // det A < 0 : reflection (still exactly U2*V2h)
        double inv = 1.0 / h2;
        q00 = (a - d) * inv;  q01 = (bb + c) * inv;
        q10 = (bb + c) * inv; q11 = (d - a) * inv;
        sgn = -1.0;
    }

    double sx = Sx * invW, sy = Sy * invW;
    double tx = Tx * invW, ty = Ty * invW;

    // t1 = src_centroid - R^T * tgt_centroid
    double t1x = sx - (q00 * tx + q10 * ty);
    double t1y = sy - (q01 * tx + q11 * ty);
    // t_out = -R * t1
    double ox = -(q00 * t1x + q01 * t1y);
    double oy = -(q10 * t1x + q11 * t1y);

    // Output 0: R_tgt_src.transpose(0,2,1), row-major per batch.
    float* R = out + (size_t)b * 9;
    R[0] = (float)q00; R[1] = (float)q10; R[2] = 0.0f;
    R[3] = (float)q01; R[4] = (float)q11; R[5] = 0.0f;
    R[6] = 0.0f;       R[7] = 0.0f;       R[8] = (float)sgn;

    // Output 1: t_src_tgt_intgt, (B,3,1) appended after the B*9 rotations.
    float* T = out + (size_t)B * 9 + (size_t)b * 3;
    T[0] = (float)ox; T[1] = (float)oy; T[2] = 0.0f;
}

extern "C" void kernel_launch(void* const* d_in, const int* in_sizes, int n_in,
                              void* d_out, int out_size, void* d_ws, size_t ws_size,
                              hipStream_t stream) {
    const float* kp = (const float*)d_in[0];  // (B*2, N, 2) f32
    const float* tg = (const float*)d_in[1];  // (B,   N, 2) f32
    const float* wt = (const float*)d_in[2];  // (B, 1, N)   f32
    float* out = (float*)d_out;               // B*9 + B*3 f32

    const int B = out_size / 12;              // 64
    const int N = in_sizes[2] / B;            // 100000
    const int npairs = N / 2;                 // N is even
    const int BPB = 32;                       // blocks per batch -> 2048 blocks
                                              // = 8 blocks/CU = full 32 waves/CU

    // No memset: svd_reduce writes every partial slot, svd_finalize reads
    // exactly those slots. (d_ws poison is irrelevant.)
    dim3 grid(BPB, B);
    svd_reduce<<<grid, 256, 0, stream>>>(
        (const float4*)kp, (const float4*)tg, (const float2*)wt,
        (double*)d_ws, npairs, BPB);

    svd_finalize<<<B, 64, 0, stream>>>((const double*)d_ws, out, B, BPB);
}